// Round 1
// baseline (705.315 us; speedup 1.0000x reference)
//
#include <hip/hip_runtime.h>
#include <hip/hip_bf16.h>

// Problem constants
#define BATCH 16
#define QLEN 32
#define KVLEN 4096
#define DMODEL 1024
#define NHEAD 16
#define DHEAD 64
// S = KVLEN + QLEN = 4128 = 64 full tiles of 64 + one 32-row tail tile

typedef short bf16x8 __attribute__((ext_vector_type(8)));
typedef float f32x4 __attribute__((ext_vector_type(4)));

// fp32 -> bf16 (round-to-nearest-even), bit pattern as ushort
__device__ __forceinline__ unsigned short f2bf(float f) {
    unsigned int u = __float_as_uint(f);
    unsigned int r = (u + 0x7fffu + ((u >> 16) & 1u)) >> 16;
    return (unsigned short)r;
}

__device__ __forceinline__ unsigned int pack2(float a, float b) {
    return (unsigned int)f2bf(a) | ((unsigned int)f2bf(b) << 16);
}

__device__ __forceinline__ bf16x8 cvt8(float4 a, float4 b) {
    bf16x8 t;
    t[0] = (short)f2bf(a.x); t[1] = (short)f2bf(a.y);
    t[2] = (short)f2bf(a.z); t[3] = (short)f2bf(a.w);
    t[4] = (short)f2bf(b.x); t[5] = (short)f2bf(b.y);
    t[6] = (short)f2bf(b.z); t[7] = (short)f2bf(b.w);
    return t;
}

// ---------------------------------------------------------------------------
// GEMM body: out[m0:m0+128, ncol:ncol+64] = A[512,1024] @ W[1024,1024] (+bias)
// fp32 in/out, bf16 MFMA 16x16x32 inside. 256 threads = 4 waves (2x2 of 64x32).
// LDS tiles padded to stride 40 halves (80 B = 20 banks -> conflict-free b128).
// ---------------------------------------------------------------------------
template <bool HAS_BIAS>
__device__ void gemm_body(const float* __restrict__ A, const float* __restrict__ W,
                          const float* __restrict__ bias, float* __restrict__ out,
                          int m0, int ncol, short* As, short* WT) {
    const int tid = threadIdx.x;
    const int l = tid & 63, w = tid >> 6;
    const int x = l & 15, g = l >> 4;
    const int wm = w >> 1, wn = w & 1;

    f32x4 acc[4][2] = {};

    for (int ko = 0; ko < 32; ++ko) {
        // stage A tile [128][32] -> As (bf16, row-major, stride 40)
#pragma unroll
        for (int c = 0; c < 4; ++c) {
            int e = tid * 4 + c * 1024;
            int row = e >> 5, col = e & 31;
            float4 v = *reinterpret_cast<const float4*>(
                &A[(size_t)(m0 + row) * DMODEL + ko * 32 + col]);
            short4 s4 = make_short4((short)f2bf(v.x), (short)f2bf(v.y),
                                    (short)f2bf(v.z), (short)f2bf(v.w));
            *reinterpret_cast<short4*>(&As[row * 40 + col]) = s4;
        }
        // stage W tile [32][64] transposed -> WT[n][k] (stride 40)
#pragma unroll
        for (int c = 0; c < 2; ++c) {
            int e = tid * 4 + c * 1024;
            int kr = e >> 6, nc = e & 63;
            float4 v = *reinterpret_cast<const float4*>(
                &W[(size_t)(ko * 32 + kr) * DMODEL + ncol + nc]);
            WT[(nc + 0) * 40 + kr] = (short)f2bf(v.x);
            WT[(nc + 1) * 40 + kr] = (short)f2bf(v.y);
            WT[(nc + 2) * 40 + kr] = (short)f2bf(v.z);
            WT[(nc + 3) * 40 + kr] = (short)f2bf(v.w);
        }
        __syncthreads();

        bf16x8 af[4], bf[2];
#pragma unroll
        for (int mi = 0; mi < 4; ++mi)
            af[mi] = *reinterpret_cast<const bf16x8*>(
                &As[(wm * 64 + mi * 16 + x) * 40 + g * 8]);
#pragma unroll
        for (int nj = 0; nj < 2; ++nj)
            bf[nj] = *reinterpret_cast<const bf16x8*>(
                &WT[(wn * 32 + nj * 16 + x) * 40 + g * 8]);
#pragma unroll
        for (int mi = 0; mi < 4; ++mi)
#pragma unroll
            for (int nj = 0; nj < 2; ++nj)
                acc[mi][nj] = __builtin_amdgcn_mfma_f32_16x16x32_bf16(
                    af[mi], bf[nj], acc[mi][nj], 0, 0, 0);
        __syncthreads();
    }

    // epilogue: C row = g*4 + r (M), col = x (N)
#pragma unroll
    for (int nj = 0; nj < 2; ++nj) {
        int gcol = ncol + wn * 32 + nj * 16 + x;
        float bv = 0.0f;
        if (HAS_BIAS) bv = bias[gcol];
#pragma unroll
        for (int mi = 0; mi < 4; ++mi) {
#pragma unroll
            for (int r = 0; r < 4; ++r) {
                int grow = m0 + wm * 64 + mi * 16 + g * 4 + r;
                out[(size_t)grow * DMODEL + gcol] = acc[mi][nj][r] + bv;
            }
        }
    }
}

// grid (4, 48): y/16 selects {Wq->q, Wk->k, Wv->v}, (y&15)*64 = column block
__global__ __launch_bounds__(256) void proj_kernel(
    const float* __restrict__ x, const float* __restrict__ Wq,
    const float* __restrict__ bq, const float* __restrict__ Wk,
    const float* __restrict__ Wv, const float* __restrict__ bv,
    float* __restrict__ q_ws, float* __restrict__ k_ws, float* __restrict__ v_ws) {
    __shared__ short As[128 * 40];
    __shared__ short WT[64 * 40];
    int m0 = blockIdx.x * 128;
    int grp = blockIdx.y >> 4;
    int ncol = (blockIdx.y & 15) * 64;
    if (grp == 0)      gemm_body<true >(x, Wq, bq,      q_ws, m0, ncol, As, WT);
    else if (grp == 1) gemm_body<false>(x, Wk, nullptr, k_ws, m0, ncol, As, WT);
    else               gemm_body<true >(x, Wv, bv,      v_ws, m0, ncol, As, WT);
}

__global__ __launch_bounds__(256) void outproj_kernel(
    const float* __restrict__ wv, const float* __restrict__ Wo,
    const float* __restrict__ bo, float* __restrict__ out) {
    __shared__ short As[128 * 40];
    __shared__ short WT[64 * 40];
    gemm_body<true>(wv, Wo, bo, out, blockIdx.x * 128, blockIdx.y * 64, As, WT);
}

// ---------------------------------------------------------------------------
// Attention: one block per (b,h). 4 waves, round-robin over s-tiles of 64.
// Swapped QK^T: C[s][q] = mfma(A=K_tile, B=Q). Online softmax per wave,
// P repacked via per-wave LDS ([q][s], stride 72 halves) into PV B-operand.
// PV: O'[d][q] = mfma(A=V^T frags (strided scalar loads), B=P).
// Final cross-wave merge (m,l,O) in LDS, write fp32 wv.
// ---------------------------------------------------------------------------
__global__ __launch_bounds__(256, 1) void attn_kernel(
    const float* __restrict__ cache_k, const float* __restrict__ cache_v,
    const float* __restrict__ q_ws, const float* __restrict__ k_ws,
    const float* __restrict__ v_ws, float* __restrict__ wv_ws) {
    __shared__ unsigned short Plds[4][32][72];  // [wave][q][s] bf16
    __shared__ float Olds[4][32][68];           // [wave][q][d] fp32
    __shared__ float red_m[4][2][16];
    __shared__ float red_l[4][2][16];

    const int bid = blockIdx.x;
    const int b = bid >> 4, h = bid & 15;
    const int tid = threadIdx.x;
    const int l = tid & 63, w = tid >> 6;
    const int x = l & 15, g = l >> 4;

    // Q B-fragments (held for whole kernel); fold the full 1/sqrt(DH)=1/8 scale
    bf16x8 qf[2][2];  // [kg][qg]
#pragma unroll
    for (int qg = 0; qg < 2; ++qg) {
#pragma unroll
        for (int kg = 0; kg < 2; ++kg) {
            const float* qp = &q_ws[(size_t)(b * QLEN + qg * 16 + x) * DMODEL +
                                    h * DHEAD + kg * 32 + g * 8];
            float4 v0 = *reinterpret_cast<const float4*>(qp);
            float4 v1 = *reinterpret_cast<const float4*>(qp + 4);
            const float s = 0.125f;
            float4 a = make_float4(v0.x * s, v0.y * s, v0.z * s, v0.w * s);
            float4 c2 = make_float4(v1.x * s, v1.y * s, v1.z * s, v1.w * s);
            qf[kg][qg] = cvt8(a, c2);
        }
    }

    float m_run[2] = {-1e30f, -1e30f};
    float l_run[2] = {0.0f, 0.0f};
    f32x4 Oacc[4][2] = {};  // [dg][qg]

    for (int t = w; t < 65; t += 4) {
        const int s0 = t * 64;
        const bool cur = (t == 64);  // 32-row tail tile from current k/v
        const float* Kb = cur ? &k_ws[(size_t)b * QLEN * DMODEL]
                              : &cache_k[(size_t)b * KVLEN * DMODEL];
        const float* Vb = cur ? &v_ws[(size_t)b * QLEN * DMODEL]
                              : &cache_v[(size_t)b * KVLEN * DMODEL];

        // K A-fragments: lane row s = sg*16+x, k-dim d = kg*32 + g*8 + j
        bf16x8 ka[4][2];
#pragma unroll
        for (int sg = 0; sg < 4; ++sg) {
            int srow = sg * 16 + x;
            srow = cur ? (srow > QLEN - 1 ? QLEN - 1 : srow) : (s0 + srow);
            const float* kp = &Kb[(size_t)srow * DMODEL + h * DHEAD + g * 8];
#pragma unroll
            for (int kg = 0; kg < 2; ++kg) {
                float4 v0 = *reinterpret_cast<const float4*>(kp + kg * 32);
                float4 v1 = *reinterpret_cast<const float4*>(kp + kg * 32 + 4);
                ka[sg][kg] = cvt8(v0, v1);
            }
        }

        // QK^T (swapped): c[sg][qg], rows = s, cols = q
        f32x4 c[4][2] = {};
#pragma unroll
        for (int sg = 0; sg < 4; ++sg) {
#pragma unroll
            for (int qg = 0; qg < 2; ++qg) {
                c[sg][qg] = __builtin_amdgcn_mfma_f32_16x16x32_bf16(
                    ka[sg][0], qf[0][qg], c[sg][qg], 0, 0, 0);
                c[sg][qg] = __builtin_amdgcn_mfma_f32_16x16x32_bf16(
                    ka[sg][1], qf[1][qg], c[sg][qg], 0, 0, 0);
            }
        }
        if (cur) {  // rows 32..63 of tail tile are invalid
#pragma unroll
            for (int qg = 0; qg < 2; ++qg)
#pragma unroll
                for (int r = 0; r < 4; ++r) {
                    c[2][qg][r] = -1e30f;
                    c[3][qg][r] = -1e30f;
                }
        }

        // online softmax (per lane: q = qg*16 + x; s spread over sg, r, and g)
        float sc[2];
#pragma unroll
        for (int qg = 0; qg < 2; ++qg) {
            float mx = c[0][qg][0];
#pragma unroll
            for (int sg = 0; sg < 4; ++sg)
#pragma unroll
                for (int r = 0; r < 4; ++r) mx = fmaxf(mx, c[sg][qg][r]);
            mx = fmaxf(mx, __shfl_xor(mx, 16));
            mx = fmaxf(mx, __shfl_xor(mx, 32));
            float mn = fmaxf(m_run[qg], mx);
            sc[qg] = __expf(m_run[qg] - mn);
            m_run[qg] = mn;
            float rs = 0.0f;
#pragma unroll
            for (int sg = 0; sg < 4; ++sg)
#pragma unroll
                for (int r = 0; r < 4; ++r) {
                    float p = __expf(c[sg][qg][r] - mn);
                    c[sg][qg][r] = p;
                    rs += p;
                }
            rs += __shfl_xor(rs, 16);
            rs += __shfl_xor(rs, 32);
            l_run[qg] = l_run[qg] * sc[qg] + rs;
        }

        // rescale running O
#pragma unroll
        for (int dg = 0; dg < 4; ++dg)
#pragma unroll
            for (int qg = 0; qg < 2; ++qg)
#pragma unroll
                for (int r = 0; r < 4; ++r) Oacc[dg][qg][r] *= sc[qg];

        // P -> per-wave LDS [q][s] (bf16)
#pragma unroll
        for (int sg = 0; sg < 4; ++sg)
#pragma unroll
            for (int qg = 0; qg < 2; ++qg) {
                unsigned int w0 = pack2(c[sg][qg][0], c[sg][qg][1]);
                unsigned int w1 = pack2(c[sg][qg][2], c[sg][qg][3]);
                unsigned short* p = &Plds[w][qg * 16 + x][sg * 16 + g * 4];
                *reinterpret_cast<unsigned int*>(p) = w0;
                *reinterpret_cast<unsigned int*>(p + 2) = w1;
            }
        // P B-fragments: lane col q = qg*16+x, k-dim s = kg*32 + g*8 + j
        bf16x8 pb[2][2];
#pragma unroll
        for (int kg = 0; kg < 2; ++kg)
#pragma unroll
            for (int qg = 0; qg < 2; ++qg)
                pb[kg][qg] = *reinterpret_cast<const bf16x8*>(
                    &Plds[w][qg * 16 + x][kg * 32 + g * 8]);

        // V^T A-fragments: lane row d = dg*16+x, k-dim s = kg*32 + g*8 + j
        bf16x8 va[4][2];
#pragma unroll
        for (int dg = 0; dg < 4; ++dg)
#pragma unroll
            for (int kg = 0; kg < 2; ++kg) {
                bf16x8 tt;
#pragma unroll
                for (int j = 0; j < 8; ++j) {
                    int sv = kg * 32 + g * 8 + j;
                    int srow = cur ? (sv > QLEN - 1 ? QLEN - 1 : sv) : (s0 + sv);
                    tt[j] = (short)f2bf(
                        Vb[(size_t)srow * DMODEL + h * DHEAD + dg * 16 + x]);
                }
                va[dg][kg] = tt;
            }

        // PV: O'[d][q]
#pragma unroll
        for (int dg = 0; dg < 4; ++dg)
#pragma unroll
            for (int qg = 0; qg < 2; ++qg) {
                Oacc[dg][qg] = __builtin_amdgcn_mfma_f32_16x16x32_bf16(
                    va[dg][0], pb[0][qg], Oacc[dg][qg], 0, 0, 0);
                Oacc[dg][qg] = __builtin_amdgcn_mfma_f32_16x16x32_bf16(
                    va[dg][1], pb[1][qg], Oacc[dg][qg], 0, 0, 0);
            }
    }

    // ---- cross-wave merge ----
    if (l < 16) {
#pragma unroll
        for (int qg = 0; qg < 2; ++qg) {
            red_m[w][qg][l] = m_run[qg];
            red_l[w][qg][l] = l_run[qg];
        }
    }
    __syncthreads();

    float cself[2];
#pragma unroll
    for (int qg = 0; qg < 2; ++qg) {
        float M = red_m[0][qg][x];
#pragma unroll
        for (int ww = 1; ww < 4; ++ww) M = fmaxf(M, red_m[ww][qg][x]);
        cself[qg] = __expf(m_run[qg] - M);
    }
#pragma unroll
    for (int dg = 0; dg < 4; ++dg)
#pragma unroll
        for (int qg = 0; qg < 2; ++qg) {
            f32x4 v = Oacc[dg][qg];
            v[0] *= cself[qg]; v[1] *= cself[qg];
            v[2] *= cself[qg]; v[3] *= cself[qg];
            *reinterpret_cast<f32x4*>(&Olds[w][qg * 16 + x][dg * 16 + g * 4]) = v;
        }
    __syncthreads();

    // 256 threads x 8 floats: sum 4 wave partials, normalize, write wv
    {
        int q = tid >> 3;
        int d0 = (tid & 7) * 8;
        int qg = q >> 4, xq = q & 15;
        float M = red_m[0][qg][xq];
#pragma unroll
        for (int ww = 1; ww < 4; ++ww) M = fmaxf(M, red_m[ww][qg][xq]);
        float L = 0.0f;
#pragma unroll
        for (int ww = 0; ww < 4; ++ww)
            L += __expf(red_m[ww][qg][xq] - M) * red_l[ww][qg][xq];
        float inv = 1.0f / L;
        float o[8] = {};
#pragma unroll
        for (int ww = 0; ww < 4; ++ww) {
            float4 a0 = *reinterpret_cast<const float4*>(&Olds[ww][q][d0]);
            float4 a1 = *reinterpret_cast<const float4*>(&Olds[ww][q][d0 + 4]);
            o[0] += a0.x; o[1] += a0.y; o[2] += a0.z; o[3] += a0.w;
            o[4] += a1.x; o[5] += a1.y; o[6] += a1.z; o[7] += a1.w;
        }
        float* op = &wv_ws[(size_t)(b * QLEN + q) * DMODEL + h * DHEAD + d0];
        float4 w0 = make_float4(o[0] * inv, o[1] * inv, o[2] * inv, o[3] * inv);
        float4 w1 = make_float4(o[4] * inv, o[5] * inv, o[6] * inv, o[7] * inv);
        *reinterpret_cast<float4*>(op) = w0;
        *reinterpret_cast<float4*>(op + 4) = w1;
    }
}

extern "C" void kernel_launch(void* const* d_in, const int* in_sizes, int n_in,
                              void* d_out, int out_size, void* d_ws, size_t ws_size,
                              hipStream_t stream) {
    (void)in_sizes; (void)n_in; (void)out_size; (void)ws_size;
    const float* x       = (const float*)d_in[0];
    const float* cache_k = (const float*)d_in[1];
    const float* cache_v = (const float*)d_in[2];
    const float* Wq      = (const float*)d_in[3];
    const float* bq      = (const float*)d_in[4];
    const float* Wk      = (const float*)d_in[5];
    const float* Wv      = (const float*)d_in[6];
    const float* bv      = (const float*)d_in[7];
    const float* Wo      = (const float*)d_in[8];
    const float* bo      = (const float*)d_in[9];
    float* out = (float*)d_out;

    float* ws    = (float*)d_ws;                 // needs 8 MB of d_ws
    float* q_ws  = ws;                           // [512][1024]
    float* k_ws  = ws + 1 * 512 * 1024;          // [512][1024] (current k)
    float* v_ws  = ws + 2 * 512 * 1024;          // [512][1024] (current v)
    float* wv_ws = ws + 3 * 512 * 1024;          // [512][1024]

    proj_kernel<<<dim3(4, 48), 256, 0, stream>>>(x, Wq, bq, Wk, Wv, bv,
                                                 q_ws, k_ws, v_ws);
    attn_kernel<<<dim3(256), 256, 0, stream>>>(cache_k, cache_v, q_ws, k_ws,
                                               v_ws, wv_ws);
    outproj_kernel<<<dim3(4, 16), 256, 0, stream>>>(wv_ws, Wo, bo, out);
}

// Round 2
// 647.206 us; speedup vs baseline: 1.0898x; 1.0898x over previous
//
#include <hip/hip_runtime.h>
#include <hip/hip_bf16.h>

#define BATCH 16
#define QLEN 32
#define KVLEN 4096
#define DMODEL 1024
#define NHEAD 16
#define DHEAD 64
// S = 4128 = 64 full tiles of 64 + one 32-row tail tile (t=64)
// slices: 4 splits (grid.y) x 4 waves = 16 independent s-slices per (b,h)

typedef short bf16x8 __attribute__((ext_vector_type(8)));
typedef float f32x4 __attribute__((ext_vector_type(4)));

// fp32 -> bf16 (round-to-nearest-even), bit pattern as ushort
__device__ __forceinline__ unsigned short f2bf(float f) {
    unsigned int u = __float_as_uint(f);
    unsigned int r = (u + 0x7fffu + ((u >> 16) & 1u)) >> 16;
    return (unsigned short)r;
}

__device__ __forceinline__ unsigned int pack2(float a, float b) {
    return (unsigned int)f2bf(a) | ((unsigned int)f2bf(b) << 16);
}

__device__ __forceinline__ bf16x8 cvt8(float4 a, float4 b) {
    bf16x8 t;
    t[0] = (short)f2bf(a.x); t[1] = (short)f2bf(a.y);
    t[2] = (short)f2bf(a.z); t[3] = (short)f2bf(a.w);
    t[4] = (short)f2bf(b.x); t[5] = (short)f2bf(b.y);
    t[6] = (short)f2bf(b.z); t[7] = (short)f2bf(b.w);
    return t;
}

// ---------------------------------------------------------------------------
// prep 1: x [512][1024] f32 -> bf16
// ---------------------------------------------------------------------------
__global__ __launch_bounds__(256) void convert_x_kernel(
    const float* __restrict__ x, unsigned short* __restrict__ xb) {
    int gidx = (blockIdx.x * 256 + threadIdx.x) * 8;
    float4 a = *reinterpret_cast<const float4*>(&x[gidx]);
    float4 b = *reinterpret_cast<const float4*>(&x[gidx + 4]);
    *reinterpret_cast<bf16x8*>(&xb[gidx]) = cvt8(a, b);
}

// ---------------------------------------------------------------------------
// prep 2: W[k][n] f32 -> WT[n][k] bf16, 64x64 tiles via LDS. z selects matrix.
// ---------------------------------------------------------------------------
__global__ __launch_bounds__(256) void transpose_w_kernel(
    const float* __restrict__ Wq, const float* __restrict__ Wk,
    const float* __restrict__ Wv, const float* __restrict__ Wo,
    unsigned short* __restrict__ WT_all) {
    __shared__ unsigned short T[64 * 72];
    const int z = blockIdx.z;
    const float* W = (z == 0) ? Wq : (z == 1) ? Wk : (z == 2) ? Wv : Wo;
    unsigned short* WT = WT_all + (size_t)z * DMODEL * DMODEL;
    const int n0 = blockIdx.x * 64, k0 = blockIdx.y * 64;
    const int tid = threadIdx.x;
    const int col4 = tid & 15, krow = tid >> 4;
#pragma unroll
    for (int p = 0; p < 4; ++p) {
        int k = krow + p * 16;
        float4 v = *reinterpret_cast<const float4*>(
            &W[(size_t)(k0 + k) * DMODEL + n0 + col4 * 4]);
        T[(col4 * 4 + 0) * 72 + k] = f2bf(v.x);
        T[(col4 * 4 + 1) * 72 + k] = f2bf(v.y);
        T[(col4 * 4 + 2) * 72 + k] = f2bf(v.z);
        T[(col4 * 4 + 3) * 72 + k] = f2bf(v.w);
    }
    __syncthreads();
    const int c8 = tid & 7;
#pragma unroll
    for (int p = 0; p < 2; ++p) {
        int n = (tid >> 3) + p * 32;
        bf16x8 v = *reinterpret_cast<const bf16x8*>(&T[n * 72 + c8 * 8]);
        *reinterpret_cast<bf16x8*>(&WT[(size_t)(n0 + n) * DMODEL + k0 + c8 * 8]) = v;
    }
}

// ---------------------------------------------------------------------------
// GEMM: out[m0:m0+128, ncol:ncol+64] = A[512,1024]bf16 @ BT[n][k]bf16
// 256 thr = 4 waves (2x2 of 64x32). BK=64, LDS stride 72 halves (<=2-way).
// ---------------------------------------------------------------------------
template <bool HAS_BIAS, bool BF16_OUT>
__device__ __forceinline__ void gemm_body(
    const unsigned short* __restrict__ A, const unsigned short* __restrict__ BT,
    const float* __restrict__ bias, float scale, void* __restrict__ outp,
    int m0, int ncol, unsigned short* As, unsigned short* Bs) {
    const int tid = threadIdx.x;
    const int l = tid & 63, w = tid >> 6;
    const int x = l & 15, g = l >> 4;
    const int wm = w >> 1, wn = w & 1;
    const int rowS = tid >> 3, colS = (tid & 7) * 8;

    f32x4 acc[4][2] = {};

    for (int ko = 0; ko < 16; ++ko) {
#pragma unroll
        for (int c = 0; c < 4; ++c) {
            int row = rowS + c * 32;
            bf16x8 v = *reinterpret_cast<const bf16x8*>(
                &A[(size_t)(m0 + row) * DMODEL + ko * 64 + colS]);
            *reinterpret_cast<bf16x8*>(&As[row * 72 + colS]) = v;
        }
#pragma unroll
        for (int c = 0; c < 2; ++c) {
            int row = rowS + c * 32;
            bf16x8 v = *reinterpret_cast<const bf16x8*>(
                &BT[(size_t)(ncol + row) * DMODEL + ko * 64 + colS]);
            *reinterpret_cast<bf16x8*>(&Bs[row * 72 + colS]) = v;
        }
        __syncthreads();

        bf16x8 af[4][2], bfr[2][2];
#pragma unroll
        for (int mi = 0; mi < 4; ++mi)
#pragma unroll
            for (int kk = 0; kk < 2; ++kk)
                af[mi][kk] = *reinterpret_cast<const bf16x8*>(
                    &As[(wm * 64 + mi * 16 + x) * 72 + kk * 32 + g * 8]);
#pragma unroll
        for (int nj = 0; nj < 2; ++nj)
#pragma unroll
            for (int kk = 0; kk < 2; ++kk)
                bfr[nj][kk] = *reinterpret_cast<const bf16x8*>(
                    &Bs[(wn * 32 + nj * 16 + x) * 72 + kk * 32 + g * 8]);
#pragma unroll
        for (int kk = 0; kk < 2; ++kk)
#pragma unroll
            for (int mi = 0; mi < 4; ++mi)
#pragma unroll
                for (int nj = 0; nj < 2; ++nj)
                    acc[mi][nj] = __builtin_amdgcn_mfma_f32_16x16x32_bf16(
                        af[mi][kk], bfr[nj][kk], acc[mi][nj], 0, 0, 0);
        __syncthreads();
    }

#pragma unroll
    for (int nj = 0; nj < 2; ++nj) {
        int gcol = ncol + wn * 32 + nj * 16 + x;
        float bv = HAS_BIAS ? bias[gcol] : 0.0f;
#pragma unroll
        for (int mi = 0; mi < 4; ++mi) {
#pragma unroll
            for (int r = 0; r < 4; ++r) {
                int grow = m0 + wm * 64 + mi * 16 + g * 4 + r;
                float v = (acc[mi][nj][r] + bv) * scale;
                if (BF16_OUT)
                    ((unsigned short*)outp)[(size_t)grow * DMODEL + gcol] = f2bf(v);
                else
                    ((float*)outp)[(size_t)grow * DMODEL + gcol] = v;
            }
        }
    }
}

// grid (4, 48): y/16 selects {q,k,v}; (y&15)*64 = n block. q pre-scaled 0.125.
__global__ __launch_bounds__(256, 2) void proj_kernel(
    const unsigned short* __restrict__ xb, const unsigned short* __restrict__ WTq,
    const unsigned short* __restrict__ WTk, const unsigned short* __restrict__ WTv,
    const float* __restrict__ bq, const float* __restrict__ bv,
    unsigned short* __restrict__ qb, unsigned short* __restrict__ kb,
    unsigned short* __restrict__ vb) {
    __shared__ unsigned short As[128 * 72];
    __shared__ unsigned short Bs[64 * 72];
    int m0 = blockIdx.x * 128;
    int grp = blockIdx.y >> 4;
    int ncol = (blockIdx.y & 15) * 64;
    if (grp == 0)
        gemm_body<true, true>(xb, WTq, bq, 0.125f, qb, m0, ncol, As, Bs);
    else if (grp == 1)
        gemm_body<false, true>(xb, WTk, nullptr, 1.0f, kb, m0, ncol, As, Bs);
    else
        gemm_body<true, true>(xb, WTv, bv, 1.0f, vb, m0, ncol, As, Bs);
}

__global__ __launch_bounds__(256, 2) void outproj_kernel(
    const unsigned short* __restrict__ wvb, const unsigned short* __restrict__ WTo,
    const float* __restrict__ bo, float* __restrict__ out) {
    __shared__ unsigned short As[128 * 72];
    __shared__ unsigned short Bs[64 * 72];
    gemm_body<true, false>(wvb, WTo, bo, 1.0f, out, blockIdx.x * 128,
                           blockIdx.y * 64, As, Bs);
}

// ---------------------------------------------------------------------------
// Attention partials. grid (256 bh, 4 splits), 4 waves. slice = split*4+w,
// tiles t = slice + 16*i (t<65). Swapped QK^T (C[s][q]), online softmax,
// P repack via per-wave LDS, PV -> O'[d][q]. Writes (m,l,O) per slice.
// ---------------------------------------------------------------------------
__global__ __launch_bounds__(256, 4) void attn_kernel(
    const float* __restrict__ cache_k, const float* __restrict__ cache_v,
    const unsigned short* __restrict__ qb, const unsigned short* __restrict__ kb,
    const unsigned short* __restrict__ vb, float* __restrict__ pm,
    float* __restrict__ pl, float* __restrict__ pO) {
    __shared__ unsigned short Plds[4][32][72];

    const int bid = blockIdx.x;
    const int b = bid >> 4, h = bid & 15;
    const int split = blockIdx.y;
    const int tid = threadIdx.x;
    const int l = tid & 63, w = tid >> 6;
    const int x = l & 15, g = l >> 4;
    const int slice = split * 4 + w;

    // Q B-fragments (bf16, scale already folded by proj)
    bf16x8 qf[2][2];  // [kg][qg]
#pragma unroll
    for (int qg = 0; qg < 2; ++qg)
#pragma unroll
        for (int kg = 0; kg < 2; ++kg)
            qf[kg][qg] = *reinterpret_cast<const bf16x8*>(
                &qb[(size_t)(b * QLEN + qg * 16 + x) * DMODEL + h * DHEAD +
                    kg * 32 + g * 8]);

    float m_run[2] = {-1e30f, -1e30f};
    float l_run[2] = {0.0f, 0.0f};
    f32x4 Oacc[4][2] = {};  // [dg][qg], C[d][q]

    for (int t = slice; t < 65; t += 16) {
        const bool cur = (t == 64);
        const int s0 = t * 64;

        // K A-fragments: row s = sg*16+x, k-dim = kg*32+g*8..+7
        bf16x8 ka[4][2];
        if (cur) {
#pragma unroll
            for (int sg = 0; sg < 4; ++sg) {
                int srow = sg * 16 + x;
                srow = srow > QLEN - 1 ? QLEN - 1 : srow;
                const unsigned short* kp =
                    &kb[(size_t)(b * QLEN + srow) * DMODEL + h * DHEAD + g * 8];
#pragma unroll
                for (int kg = 0; kg < 2; ++kg)
                    ka[sg][kg] = *reinterpret_cast<const bf16x8*>(kp + kg * 32);
            }
        } else {
            const float* Kb = &cache_k[(size_t)b * KVLEN * DMODEL];
#pragma unroll
            for (int sg = 0; sg < 4; ++sg) {
                const float* kp = &Kb[(size_t)(s0 + sg * 16 + x) * DMODEL +
                                      h * DHEAD + g * 8];
#pragma unroll
                for (int kg = 0; kg < 2; ++kg) {
                    float4 v0 = *reinterpret_cast<const float4*>(kp + kg * 32);
                    float4 v1 = *reinterpret_cast<const float4*>(kp + kg * 32 + 4);
                    ka[sg][kg] = cvt8(v0, v1);
                }
            }
        }

        f32x4 c[4][2] = {};
#pragma unroll
        for (int sg = 0; sg < 4; ++sg)
#pragma unroll
            for (int qg = 0; qg < 2; ++qg) {
                c[sg][qg] = __builtin_amdgcn_mfma_f32_16x16x32_bf16(
                    ka[sg][0], qf[0][qg], c[sg][qg], 0, 0, 0);
                c[sg][qg] = __builtin_amdgcn_mfma_f32_16x16x32_bf16(
                    ka[sg][1], qf[1][qg], c[sg][qg], 0, 0, 0);
            }
        if (cur) {
#pragma unroll
            for (int qg = 0; qg < 2; ++qg)
#pragma unroll
                for (int r = 0; r < 4; ++r) {
                    c[2][qg][r] = -1e30f;
                    c[3][qg][r] = -1e30f;
                }
        }

        // online softmax; lane's q = qg*16+x; s spread over sg,r and lanes g
        float sc[2];
#pragma unroll
        for (int qg = 0; qg < 2; ++qg) {
            float mx = c[0][qg][0];
#pragma unroll
            for (int sg = 0; sg < 4; ++sg)
#pragma unroll
                for (int r = 0; r < 4; ++r) mx = fmaxf(mx, c[sg][qg][r]);
            mx = fmaxf(mx, __shfl_xor(mx, 16));
            mx = fmaxf(mx, __shfl_xor(mx, 32));
            float mn = fmaxf(m_run[qg], mx);
            sc[qg] = __expf(m_run[qg] - mn);
            m_run[qg] = mn;
            float rs = 0.0f;
#pragma unroll
            for (int sg = 0; sg < 4; ++sg)
#pragma unroll
                for (int r = 0; r < 4; ++r) {
                    float p = __expf(c[sg][qg][r] - mn);
                    c[sg][qg][r] = p;
                    rs += p;
                }
            rs += __shfl_xor(rs, 16);
            rs += __shfl_xor(rs, 32);
            l_run[qg] = l_run[qg] * sc[qg] + rs;
        }

#pragma unroll
        for (int dg = 0; dg < 4; ++dg)
#pragma unroll
            for (int qg = 0; qg < 2; ++qg)
#pragma unroll
                for (int r = 0; r < 4; ++r) Oacc[dg][qg][r] *= sc[qg];

        // P -> per-wave LDS [q][s]
#pragma unroll
        for (int sg = 0; sg < 4; ++sg)
#pragma unroll
            for (int qg = 0; qg < 2; ++qg) {
                unsigned int w0 = pack2(c[sg][qg][0], c[sg][qg][1]);
                unsigned int w1 = pack2(c[sg][qg][2], c[sg][qg][3]);
                unsigned short* p = &Plds[w][qg * 16 + x][sg * 16 + g * 4];
                *reinterpret_cast<unsigned int*>(p) = w0;
                *reinterpret_cast<unsigned int*>(p + 2) = w1;
            }
        bf16x8 pb[2][2];
#pragma unroll
        for (int kg = 0; kg < 2; ++kg)
#pragma unroll
            for (int qg = 0; qg < 2; ++qg)
                pb[kg][qg] = *reinterpret_cast<const bf16x8*>(
                    &Plds[w][qg * 16 + x][kg * 32 + g * 8]);

        // V^T A-fragments: row d = dg*16+x, k-dim s = kg*32+g*8+j
        bf16x8 va[4][2];
        if (cur) {
#pragma unroll
            for (int dg = 0; dg < 4; ++dg)
#pragma unroll
                for (int kg = 0; kg < 2; ++kg) {
                    bf16x8 tt;
#pragma unroll
                    for (int j = 0; j < 8; ++j) {
                        int sv = kg * 32 + g * 8 + j;
                        int srow = sv > QLEN - 1 ? QLEN - 1 : sv;
                        tt[j] = (short)vb[(size_t)(b * QLEN + srow) * DMODEL +
                                          h * DHEAD + dg * 16 + x];
                    }
                    va[dg][kg] = tt;
                }
        } else {
            const float* Vb = &cache_v[(size_t)b * KVLEN * DMODEL];
#pragma unroll
            for (int dg = 0; dg < 4; ++dg)
#pragma unroll
                for (int kg = 0; kg < 2; ++kg) {
                    bf16x8 tt;
#pragma unroll
                    for (int j = 0; j < 8; ++j) {
                        int srow = s0 + kg * 32 + g * 8 + j;
                        tt[j] = (short)f2bf(
                            Vb[(size_t)srow * DMODEL + h * DHEAD + dg * 16 + x]);
                    }
                    va[dg][kg] = tt;
                }
        }

#pragma unroll
        for (int dg = 0; dg < 4; ++dg)
#pragma unroll
            for (int qg = 0; qg < 2; ++qg) {
                Oacc[dg][qg] = __builtin_amdgcn_mfma_f32_16x16x32_bf16(
                    va[dg][0], pb[0][qg], Oacc[dg][qg], 0, 0, 0);
                Oacc[dg][qg] = __builtin_amdgcn_mfma_f32_16x16x32_bf16(
                    va[dg][1], pb[1][qg], Oacc[dg][qg], 0, 0, 0);
            }
    }

    // write partials for this slice
    const int p = bid * 16 + slice;
    if (g == 0) {
#pragma unroll
        for (int qg = 0; qg < 2; ++qg) {
            pm[p * 32 + qg * 16 + x] = m_run[qg];
            pl[p * 32 + qg * 16 + x] = l_run[qg];
        }
    }
#pragma unroll
    for (int dg = 0; dg < 4; ++dg)
#pragma unroll
        for (int qg = 0; qg < 2; ++qg)
            *reinterpret_cast<f32x4*>(
                &pO[(size_t)(p * 32 + qg * 16 + x) * DHEAD + dg * 16 + g * 4]) =
                Oacc[dg][qg];
}

// ---------------------------------------------------------------------------
// Merge 16 slice-partials per (bh,q) row; write wv bf16 [b][q][h*64+d].
// 512 blocks x 4 waves; wave handles 4 rows; lane = d.
// ---------------------------------------------------------------------------
__global__ __launch_bounds__(256, 4) void merge_kernel(
    const float* __restrict__ pm, const float* __restrict__ pl,
    const float* __restrict__ pO, unsigned short* __restrict__ wvb) {
    const int w = threadIdx.x >> 6, d = threadIdx.x & 63;
    const int gw = blockIdx.x * 4 + w;
#pragma unroll
    for (int i = 0; i < 4; ++i) {
        int row = gw * 4 + i;           // 0..8191
        int bh = row >> 5, q = row & 31;
        int base = bh * 16;
        float M = -1e30f;
#pragma unroll
        for (int s = 0; s < 16; ++s) M = fmaxf(M, pm[(base + s) * 32 + q]);
        float L = 0.0f, O = 0.0f;
#pragma unroll
        for (int s = 0; s < 16; ++s) {
            float ws = __expf(pm[(base + s) * 32 + q] - M);
            L += ws * pl[(base + s) * 32 + q];
            O += ws * pO[(size_t)((base + s) * 32 + q) * DHEAD + d];
        }
        int b = bh >> 4, h = bh & 15;
        wvb[(size_t)(b * QLEN + q) * DMODEL + h * DHEAD + d] = f2bf(O / L);
    }
}

extern "C" void kernel_launch(void* const* d_in, const int* in_sizes, int n_in,
                              void* d_out, int out_size, void* d_ws, size_t ws_size,
                              hipStream_t stream) {
    (void)in_sizes; (void)n_in; (void)out_size; (void)ws_size;
    const float* x       = (const float*)d_in[0];
    const float* cache_k = (const float*)d_in[1];
    const float* cache_v = (const float*)d_in[2];
    const float* Wq      = (const float*)d_in[3];
    const float* bq      = (const float*)d_in[4];
    const float* Wk      = (const float*)d_in[5];
    const float* Wv      = (const float*)d_in[6];
    const float* bv      = (const float*)d_in[7];
    const float* Wo      = (const float*)d_in[8];
    const float* bo      = (const float*)d_in[9];
    float* out = (float*)d_out;

    // ws layout (bf16 region then fp32 region at 16 MB)
    unsigned short* U   = (unsigned short*)d_ws;
    unsigned short* xb  = U;                          // 512K
    unsigned short* WTq = U + (1u << 19);             // 1M each
    unsigned short* WTk = WTq + (1u << 20);
    unsigned short* WTv = WTk + (1u << 20);
    unsigned short* WTo = WTv + (1u << 20);
    unsigned short* qb  = WTo + (1u << 20);           // 512K each
    unsigned short* kb  = qb + (1u << 19);
    unsigned short* vb  = kb + (1u << 19);
    unsigned short* wvb = vb + (1u << 19);
    float* F  = (float*)((char*)d_ws + (16u << 20));
    float* pm = F;                                    // 4096*32
    float* pl = pm + 4096 * 32;
    float* pO = pl + 4096 * 32;                       // 4096*32*64

    convert_x_kernel<<<256, 256, 0, stream>>>(x, xb);
    transpose_w_kernel<<<dim3(16, 16, 4), 256, 0, stream>>>(Wq, Wk, Wv, Wo, WTq);
    proj_kernel<<<dim3(4, 48), 256, 0, stream>>>(xb, WTq, WTk, WTv, bq, bv,
                                                 qb, kb, vb);
    attn_kernel<<<dim3(256, 4), 256, 0, stream>>>(cache_k, cache_v, qb, kb, vb,
                                                  pm, pl, pO);
    merge_kernel<<<512, 256, 0, stream>>>(pm, pl, pO, wvb);
    outproj_kernel<<<dim3(4, 16), 256, 0, stream>>>(wvb, WTo, bo, out);
}